// Round 1
// baseline (85.210 us; speedup 1.0000x reference)
//
#include <hip/hip_runtime.h>
#include <math.h>

#define BS 8
#define P 8192
#define G 16
#define DIM 512

#define BLOCKS_PER_BATCH 128
#define ROWS_PER_BLOCK 64   // P / BLOCKS_PER_BATCH
#define WAVES_PER_BLOCK 4
#define ROWS_PER_WAVE 16    // ROWS_PER_BLOCK / WAVES_PER_BLOCK

__device__ __forceinline__ float smooth_l1(float d) {
    float a = fabsf(d);
    return a < 1.0f ? 0.5f * d * d : a - 0.5f;
}

__global__ __launch_bounds__(256, 4)
void det_main(const float* __restrict__ v,
              const float* __restrict__ gt,
              const float* __restrict__ rois,
              const float* __restrict__ labels,
              const float* __restrict__ pre_score,
              const float* __restrict__ cls_w,
              const float* __restrict__ cls_b,
              const float* __restrict__ reg_w,
              const float* __restrict__ reg_b,
              float* __restrict__ partials)   // [BS][3]: cnum, cden, l1
{
    const int tid  = threadIdx.x;
    const int lane = tid & 63;
    const int wave = tid >> 6;
    const int b    = blockIdx.x / BLOCKS_PER_BATCH;
    const int blk  = blockIdx.x % BLOCKS_PER_BATCH;
    const int p0   = blk * ROWS_PER_BLOCK + wave * ROWS_PER_WAVE;

    // ---- per-lane weight fragments: w[c][j] = W_c[lane*8+j]; c 0..3 = cls, 4..7 = reg
    float w[8][8];
    #pragma unroll
    for (int c = 0; c < 4; ++c) {
        const float4* cw = (const float4*)(cls_w + c * DIM + lane * 8);
        float4 x0 = cw[0], x1 = cw[1];
        w[c][0] = x0.x; w[c][1] = x0.y; w[c][2] = x0.z; w[c][3] = x0.w;
        w[c][4] = x1.x; w[c][5] = x1.y; w[c][6] = x1.z; w[c][7] = x1.w;
        const float4* rw = (const float4*)(reg_w + c * DIM + lane * 8);
        float4 y0 = rw[0], y1 = rw[1];
        w[c+4][0] = y0.x; w[c+4][1] = y0.y; w[c+4][2] = y0.z; w[c+4][3] = y0.w;
        w[c+4][4] = y1.x; w[c+4][5] = y1.y; w[c+4][6] = y1.z; w[c+4][7] = y1.w;
    }
    const float cb0 = cls_b[0], cb1 = cls_b[1], cb2 = cls_b[2], cb3 = cls_b[3];
    const float rb0 = reg_b[0], rb1 = reg_b[1], rb2 = reg_b[2], rb3 = reg_b[3];

    // ---- GT boxes for this batch into LDS, then per-lane register copy (lane uses gt[lane&15])
    __shared__ float s_gt[G * 4];
    __shared__ int   s_lab;
    if (tid < G * 4) s_gt[tid] = gt[b * G * 4 + tid];
    if (tid == 0) {
        const float* lb = labels + b * 4;
        int li = 0; float lm = lb[0];
        #pragma unroll
        for (int i = 1; i < 4; ++i) if (lb[i] > lm) { lm = lb[i]; li = i; }
        s_lab = li;
    }
    __syncthreads();
    const int lab = s_lab;
    const int gsel = lane & 15;
    const float g0 = s_gt[gsel * 4 + 0], g1 = s_gt[gsel * 4 + 1];
    const float g2 = s_gt[gsel * 4 + 2], g3 = s_gt[gsel * 4 + 3];
    const float area_g = (g2 - g0) * (g3 - g1);

    float acc_cnum = 0.0f, acc_cden = 0.0f, acc_l1 = 0.0f;

    // ---- main loop: one v-row per wave-iteration, 1-row prefetch
    const float4* vp = (const float4*)(v + ((size_t)b * P + p0) * DIM) + lane * 2;
    float4 a0 = vp[0], a1 = vp[1];
    for (int rr = 0; rr < ROWS_PER_WAVE; ++rr) {
        const int p = p0 + rr;
        float4 c0v = a0, c1v = a1;
        if (rr + 1 < ROWS_PER_WAVE) { vp += DIM / 4; a0 = vp[0]; a1 = vp[1]; }

        float d[8];
        #pragma unroll
        for (int c = 0; c < 8; ++c) {
            d[c] = c0v.x * w[c][0] + c0v.y * w[c][1] + c0v.z * w[c][2] + c0v.w * w[c][3]
                 + c1v.x * w[c][4] + c1v.y * w[c][5] + c1v.z * w[c][6] + c1v.w * w[c][7];
        }
        // full-wave butterfly: every lane ends with the complete 8 dot products
        #pragma unroll
        for (int off = 32; off > 0; off >>= 1) {
            #pragma unroll
            for (int c = 0; c < 8; ++c) d[c] += __shfl_xor(d[c], off, 64);
        }

        // ---- epilogue (wave-uniform after reductions)
        float4 rbox = *(const float4*)(rois + ((size_t)b * P + p) * 4);  // broadcast
        // IoU vs gt[gsel], replicated across the 4 groups of 16 lanes
        float ltx = fmaxf(g0, rbox.x), lty = fmaxf(g1, rbox.y);
        float rbx = fminf(g2, rbox.z), rby = fminf(g3, rbox.w);
        float wx = fmaxf(rbx - ltx, 0.0f), wy = fmaxf(rby - lty, 0.0f);
        float inter = wx * wy;
        float area_r = (rbox.z - rbox.x) * (rbox.w - rbox.y);
        float iou = inter / (area_g + area_r - inter);
        float biou = iou; int bidx = gsel;
        #pragma unroll
        for (int off = 8; off > 0; off >>= 1) {   // stays within each 16-lane group
            float oi = __shfl_xor(biou, off, 64);
            int   ox = __shfl_xor(bidx, off, 64);
            if (oi > biou || (oi == biou && ox < bidx)) { biou = oi; bidx = ox; }
        }
        float mask = biou > 0.5f ? 1.0f : 0.0f;

        // cross-entropy on clipped logits
        float c0 = fminf(fmaxf(d[0] + cb0, 1e-7f), 0.99999994f);
        float c1 = fminf(fmaxf(d[1] + cb1, 1e-7f), 0.99999994f);
        float c2 = fminf(fmaxf(d[2] + cb2, 1e-7f), 0.99999994f);
        float c3 = fminf(fmaxf(d[3] + cb3, 1e-7f), 0.99999994f);
        float m  = fmaxf(fmaxf(c0, c1), fmaxf(c2, c3));
        float s  = expf(c0 - m) + expf(c1 - m) + expf(c2 - m) + expf(c3 - m);
        float lse = m + logf(s);
        float csel = lab == 0 ? c0 : (lab == 1 ? c1 : (lab == 2 ? c2 : c3));
        float ce = lse - csel;
        float ps = pre_score[((size_t)b * P + p) * 4 + lab];  // broadcast

        acc_cnum += ce * ps * mask;
        acc_cden += mask;

        // regression targets from best GT
        float bg0 = s_gt[bidx * 4 + 0], bg1 = s_gt[bidx * 4 + 1];
        float bg2 = s_gt[bidx * 4 + 2], bg3 = s_gt[bidx * 4 + 3];
        float gx = (bg2 + bg0) * 0.5f, gy = (bg3 + bg1) * 0.5f;
        float gw = (bg2 - bg0) * 0.5f, gh = (bg3 - bg1) * 0.5f;
        float rx = (rbox.z + rbox.x) * 0.5f, ry = (rbox.w + rbox.y) * 0.5f;
        float rw_ = (rbox.z - rbox.x) * 0.5f, rh = (rbox.w - rbox.y) * 0.5f;
        float tx = (gx - rx) / (rw_ + 1e-8f);
        float ty = (gy - ry) / (rh + 1e-8f);
        float tw = logf(gw / (rw_ + 1e-8f));
        float th = logf(gh / (rh + 1e-8f));
        float l1v = smooth_l1(d[4] + rb0 - tx) + smooth_l1(d[5] + rb1 - ty)
                  + smooth_l1(d[6] + rb2 - tw) + smooth_l1(d[7] + rb3 - th);
        acc_l1 += l1v * mask * ps;
    }

    // ---- block reduction (values are wave-uniform; take lane 0 of each wave)
    __shared__ float s_red[WAVES_PER_BLOCK][3];
    if (lane == 0) {
        s_red[wave][0] = acc_cnum;
        s_red[wave][1] = acc_cden;
        s_red[wave][2] = acc_l1;
    }
    __syncthreads();
    if (tid == 0) {
        float a = 0.0f, bb = 0.0f, cc = 0.0f;
        #pragma unroll
        for (int wv = 0; wv < WAVES_PER_BLOCK; ++wv) {
            a  += s_red[wv][0];
            bb += s_red[wv][1];
            cc += s_red[wv][2];
        }
        atomicAdd(&partials[b * 3 + 0], a);
        atomicAdd(&partials[b * 3 + 1], bb);
        atomicAdd(&partials[b * 3 + 2], cc);
    }
}

__global__ void det_final(const float* __restrict__ partials, float* __restrict__ out)
{
    if (threadIdx.x == 0 && blockIdx.x == 0) {
        float cl = 0.0f, l1 = 0.0f;
        #pragma unroll
        for (int b = 0; b < BS; ++b) {
            cl += partials[b * 3 + 0] / (partials[b * 3 + 1] + 1e-7f);
            l1 += partials[b * 3 + 2];
        }
        out[0] = cl / ((float)BS + 1e-7f) + l1 / (float)(BS * P);
    }
}

extern "C" void kernel_launch(void* const* d_in, const int* in_sizes, int n_in,
                              void* d_out, int out_size, void* d_ws, size_t ws_size,
                              hipStream_t stream) {
    const float* v         = (const float*)d_in[0];
    const float* gt        = (const float*)d_in[1];
    const float* rois      = (const float*)d_in[2];
    const float* labels    = (const float*)d_in[3];
    const float* pre_score = (const float*)d_in[4];
    const float* cls_w     = (const float*)d_in[5];
    const float* cls_b     = (const float*)d_in[6];
    const float* reg_w     = (const float*)d_in[7];
    const float* reg_b     = (const float*)d_in[8];
    float* partials = (float*)d_ws;
    float* out      = (float*)d_out;

    hipMemsetAsync(d_ws, 0, BS * 3 * sizeof(float), stream);
    det_main<<<BS * BLOCKS_PER_BATCH, 256, 0, stream>>>(
        v, gt, rois, labels, pre_score, cls_w, cls_b, reg_w, reg_b, partials);
    det_final<<<1, 64, 0, stream>>>(partials, out);
}

// Round 2
// 44.550 us; speedup vs baseline: 1.9127x; 1.9127x over previous
//
#include <hip/hip_runtime.h>
#include <math.h>

#define BS 8
#define P 8192
#define G 16
#define DIM 512

#define BLOCK 256
#define WAVES 4                 // waves per block
#define RPG 4                   // rows per 8-lane group
#define ROWS_PER_WAVE (8 * RPG)             // 32
#define ROWS_PER_BLOCK (WAVES * ROWS_PER_WAVE)  // 128
#define BLOCKS_PER_BATCH (P / ROWS_PER_BLOCK)   // 64
#define KSTEPS (DIM / 32)       // 16: per step a group covers 32 positions

__device__ __forceinline__ float smooth_l1(float d) {
    float a = fabsf(d);
    return a < 1.0f ? 0.5f * d * d : a - 0.5f;
}

__global__ __launch_bounds__(BLOCK, 2)
void det_main(const float* __restrict__ v,
              const float* __restrict__ gt,
              const float* __restrict__ rois,
              const float* __restrict__ labels,
              const float* __restrict__ pre_score,
              const float* __restrict__ cls_w,
              const float* __restrict__ cls_b,
              const float* __restrict__ reg_w,
              const float* __restrict__ reg_b,
              float* __restrict__ partials)   // [BS][3]: cnum, cden, l1
{
    const int tid  = threadIdx.x;
    const int lane = tid & 63;
    const int wave = tid >> 6;
    const int l    = lane & 7;   // lane within group
    const int grp  = lane >> 3;  // group within wave (0..7)
    const int b    = blockIdx.x / BLOCKS_PER_BATCH;
    const int blk  = blockIdx.x % BLOCKS_PER_BATCH;
    // first row owned by this group
    const int p0   = blk * ROWS_PER_BLOCK + wave * ROWS_PER_WAVE + grp * RPG;

    __shared__ float s_w[8 * DIM];   // 16 KB: c=0..3 cls, c=4..7 reg
    __shared__ float s_gt[G * 4];
    __shared__ int   s_lab;
    __shared__ float s_red[WAVES][3];

    // ---- stage weights into LDS (flat float4 copy)
    {
        const float4* cw = (const float4*)cls_w;   // 512 float4
        const float4* rw = (const float4*)reg_w;   // 512 float4
        float4* sw = (float4*)s_w;
        #pragma unroll
        for (int i = 0; i < 2; ++i) sw[i * BLOCK + tid]       = cw[i * BLOCK + tid];
        #pragma unroll
        for (int i = 0; i < 2; ++i) sw[512 + i * BLOCK + tid] = rw[i * BLOCK + tid];
    }
    if (tid < G * 4) s_gt[tid] = gt[b * G * 4 + tid];
    if (tid == 0) {
        const float* lb = labels + b * 4;
        int li = 0; float lm = lb[0];
        #pragma unroll
        for (int i = 1; i < 4; ++i) if (lb[i] > lm) { lm = lb[i]; li = i; }
        s_lab = li;
    }
    __syncthreads();
    const int lab = s_lab;

    const float cb0 = cls_b[0], cb1 = cls_b[1], cb2 = cls_b[2], cb3 = cls_b[3];
    const float rb0 = reg_b[0], rb1 = reg_b[1], rb2 = reg_b[2], rb3 = reg_b[3];

    // ---- GEMV: acc[c][r] = partial dot of row (p0+r) with matrix c
    float acc[8][RPG];
    #pragma unroll
    for (int c = 0; c < 8; ++c)
        #pragma unroll
        for (int r = 0; r < RPG; ++r) acc[c][r] = 0.0f;

    const float* vb = v + ((size_t)b * P + p0) * DIM + l * 4;

    float4 nv[RPG];
    #pragma unroll
    for (int r = 0; r < RPG; ++r) nv[r] = *(const float4*)(vb + r * DIM);

    #pragma unroll 4
    for (int k = 0; k < KSTEPS; ++k) {
        float4 vv[RPG];
        #pragma unroll
        for (int r = 0; r < RPG; ++r) vv[r] = nv[r];
        if (k + 1 < KSTEPS) {
            #pragma unroll
            for (int r = 0; r < RPG; ++r)
                nv[r] = *(const float4*)(vb + r * DIM + (k + 1) * 32);
        }
        float4 wv[8];
        #pragma unroll
        for (int c = 0; c < 8; ++c)
            wv[c] = *(const float4*)&s_w[c * DIM + l * 4 + k * 32];
        #pragma unroll
        for (int c = 0; c < 8; ++c)
            #pragma unroll
            for (int r = 0; r < RPG; ++r)
                acc[c][r] += wv[c].x * vv[r].x + wv[c].y * vv[r].y
                           + wv[c].z * vv[r].z + wv[c].w * vv[r].w;
    }

    // ---- reduce across the 8 lanes of each group (3 butterfly steps)
    #pragma unroll
    for (int c = 0; c < 8; ++c)
        #pragma unroll
        for (int r = 0; r < RPG; ++r) {
            float x = acc[c][r];
            x += __shfl_xor(x, 1);
            x += __shfl_xor(x, 2);
            x += __shfl_xor(x, 4);
            acc[c][r] = x;   // every lane in the group now holds the full sum
        }

    // ---- epilogue: lane l (<RPG) of each group handles row p0+l
    float acc_cnum = 0.0f, acc_cden = 0.0f, acc_l1 = 0.0f;
    if (l < RPG) {
        float d[8];
        #pragma unroll
        for (int r = 0; r < RPG; ++r)
            if (l == r) {
                #pragma unroll
                for (int c = 0; c < 8; ++c) d[c] = acc[c][r];
            }
        const int p = p0 + l;
        const float4 rbox = *(const float4*)(rois + ((size_t)b * P + p) * 4);
        const float area_r = (rbox.z - rbox.x) * (rbox.w - rbox.y);

        float biou = -1.0f; int bidx = 0;
        #pragma unroll
        for (int gi = 0; gi < G; ++gi) {
            float g0 = s_gt[gi * 4 + 0], g1 = s_gt[gi * 4 + 1];
            float g2 = s_gt[gi * 4 + 2], g3 = s_gt[gi * 4 + 3];
            float ltx = fmaxf(g0, rbox.x), lty = fmaxf(g1, rbox.y);
            float rbx = fminf(g2, rbox.z), rby = fminf(g3, rbox.w);
            float wx = fmaxf(rbx - ltx, 0.0f), wy = fmaxf(rby - lty, 0.0f);
            float inter = wx * wy;
            float ag = (g2 - g0) * (g3 - g1);
            float iou = inter / (ag + area_r - inter);
            if (iou > biou) { biou = iou; bidx = gi; }
        }
        const float mask = biou > 0.5f ? 1.0f : 0.0f;

        // cross-entropy on clipped logits
        float c0 = fminf(fmaxf(d[0] + cb0, 1e-7f), 0.99999994f);
        float c1 = fminf(fmaxf(d[1] + cb1, 1e-7f), 0.99999994f);
        float c2 = fminf(fmaxf(d[2] + cb2, 1e-7f), 0.99999994f);
        float c3 = fminf(fmaxf(d[3] + cb3, 1e-7f), 0.99999994f);
        float m  = fmaxf(fmaxf(c0, c1), fmaxf(c2, c3));
        float s  = expf(c0 - m) + expf(c1 - m) + expf(c2 - m) + expf(c3 - m);
        float lse = m + logf(s);
        float csel = lab == 0 ? c0 : (lab == 1 ? c1 : (lab == 2 ? c2 : c3));
        float ce = lse - csel;
        const float ps = pre_score[((size_t)b * P + p) * 4 + lab];

        acc_cnum = ce * ps * mask;
        acc_cden = mask;

        // regression loss vs best-GT targets
        float bg0 = s_gt[bidx * 4 + 0], bg1 = s_gt[bidx * 4 + 1];
        float bg2 = s_gt[bidx * 4 + 2], bg3 = s_gt[bidx * 4 + 3];
        float gx = (bg2 + bg0) * 0.5f, gy = (bg3 + bg1) * 0.5f;
        float gw = (bg2 - bg0) * 0.5f, gh = (bg3 - bg1) * 0.5f;
        float rx = (rbox.z + rbox.x) * 0.5f, ry = (rbox.w + rbox.y) * 0.5f;
        float rw_ = (rbox.z - rbox.x) * 0.5f, rh = (rbox.w - rbox.y) * 0.5f;
        float tx = (gx - rx) / (rw_ + 1e-8f);
        float ty = (gy - ry) / (rh + 1e-8f);
        float tw = logf(gw / (rw_ + 1e-8f));
        float th = logf(gh / (rh + 1e-8f));
        float l1v = smooth_l1(d[4] + rb0 - tx) + smooth_l1(d[5] + rb1 - ty)
                  + smooth_l1(d[6] + rb2 - tw) + smooth_l1(d[7] + rb3 - th);
        acc_l1 = l1v * mask * ps;
    }

    // ---- full-wave butterfly sum of the three partials
    #pragma unroll
    for (int off = 32; off > 0; off >>= 1) {
        acc_cnum += __shfl_xor(acc_cnum, off);
        acc_cden += __shfl_xor(acc_cden, off);
        acc_l1   += __shfl_xor(acc_l1,   off);
    }
    if (lane == 0) {
        s_red[wave][0] = acc_cnum;
        s_red[wave][1] = acc_cden;
        s_red[wave][2] = acc_l1;
    }
    __syncthreads();
    if (tid == 0) {
        float a = 0.0f, bb = 0.0f, cc = 0.0f;
        #pragma unroll
        for (int wv = 0; wv < WAVES; ++wv) {
            a  += s_red[wv][0];
            bb += s_red[wv][1];
            cc += s_red[wv][2];
        }
        atomicAdd(&partials[b * 3 + 0], a);
        atomicAdd(&partials[b * 3 + 1], bb);
        atomicAdd(&partials[b * 3 + 2], cc);
    }
}

__global__ void det_final(const float* __restrict__ partials, float* __restrict__ out)
{
    if (threadIdx.x == 0 && blockIdx.x == 0) {
        float cl = 0.0f, l1 = 0.0f;
        #pragma unroll
        for (int b = 0; b < BS; ++b) {
            cl += partials[b * 3 + 0] / (partials[b * 3 + 1] + 1e-7f);
            l1 += partials[b * 3 + 2];
        }
        out[0] = cl / ((float)BS + 1e-7f) + l1 / (float)(BS * P);
    }
}

extern "C" void kernel_launch(void* const* d_in, const int* in_sizes, int n_in,
                              void* d_out, int out_size, void* d_ws, size_t ws_size,
                              hipStream_t stream) {
    const float* v         = (const float*)d_in[0];
    const float* gt        = (const float*)d_in[1];
    const float* rois      = (const float*)d_in[2];
    const float* labels    = (const float*)d_in[3];
    const float* pre_score = (const float*)d_in[4];
    const float* cls_w     = (const float*)d_in[5];
    const float* cls_b     = (const float*)d_in[6];
    const float* reg_w     = (const float*)d_in[7];
    const float* reg_b     = (const float*)d_in[8];
    float* partials = (float*)d_ws;
    float* out      = (float*)d_out;

    hipMemsetAsync(d_ws, 0, BS * 3 * sizeof(float), stream);
    det_main<<<(BS * P) / ROWS_PER_BLOCK, BLOCK, 0, stream>>>(
        v, gt, rois, labels, pre_score, cls_w, cls_b, reg_w, reg_b, partials);
    det_final<<<1, 64, 0, stream>>>(partials, out);
}